// Round 1
// baseline (21011.214 us; speedup 1.0000x reference)
//
#include <hip/hip_runtime.h>
#include <cstdint>
#include <cstddef>

// Problem constants
#define B_  8
#define T_  1024
#define C_  1024
#define H_  16
#define HS_ 64
#define BTC ((size_t)B_ * T_ * C_)   // 8,388,608 floats

// ---------------------------------------------------------------- reductions
__device__ inline float wave_sum(float v) {
#pragma unroll
  for (int off = 1; off < 64; off <<= 1) v += __shfl_xor(v, off);
  return v;
}
__device__ inline float wave_max(float v) {
#pragma unroll
  for (int off = 1; off < 64; off <<= 1) v = fmaxf(v, __shfl_xor(v, off));
  return v;
}

// ---------------------------------------------------------------- LayerNorm
// One block (256 thr) per row of C_=1024. FLIP reads x reversed along C
// (stats are flip-invariant; only the per-position gather reverses).
template <bool FLIP>
__global__ __launch_bounds__(256) void ln_rows(const float* __restrict__ x,
                                               const float* __restrict__ g,
                                               const float* __restrict__ be,
                                               float* __restrict__ out) {
  const int row = blockIdx.x;
  const int tid = threadIdx.x;
  const float* xr = x + (size_t)row * C_;
  const int c = tid * 4;
  float4 xv = *(const float4*)(xr + c);
  float s = xv.x + xv.y + xv.z + xv.w;
  float q = xv.x * xv.x + xv.y * xv.y + xv.z * xv.z + xv.w * xv.w;
  s = wave_sum(s);
  q = wave_sum(q);
  __shared__ float r1[4], r2[4];
  if ((tid & 63) == 0) { r1[tid >> 6] = s; r2[tid >> 6] = q; }
  __syncthreads();
  const float sum = r1[0] + r1[1] + r1[2] + r1[3];
  const float sq  = r2[0] + r2[1] + r2[2] + r2[3];
  const float mu  = sum * (1.f / C_);
  const float var = sq * (1.f / C_) - mu * mu;
  const float rs  = rsqrtf(var + 1e-5f);
  const float4 gv = *(const float4*)(g + c);
  const float4 bv = *(const float4*)(be + c);
  float4 ov;
  if (!FLIP) {
    ov.x = (xv.x - mu) * rs * gv.x + bv.x;
    ov.y = (xv.y - mu) * rs * gv.y + bv.y;
    ov.z = (xv.z - mu) * rs * gv.z + bv.z;
    ov.w = (xv.w - mu) * rs * gv.w + bv.w;
  } else {
    const float4 xf = *(const float4*)(xr + (C_ - 4 - c));  // holds x[C-4-c .. C-1-c]
    ov.x = (xf.w - mu) * rs * gv.x + bv.x;   // x[C-1-c]
    ov.y = (xf.z - mu) * rs * gv.y + bv.y;   // x[C-2-c]
    ov.z = (xf.y - mu) * rs * gv.z + bv.z;
    ov.w = (xf.x - mu) * rs * gv.w + bv.w;
  }
  *(float4*)(out + (size_t)row * C_ + c) = ov;
}

// LN over concat(fx,bx) rows (2C = 2048 wide), writes [B,T,2C].
__global__ __launch_bounds__(256) void ln2_rows(const float* __restrict__ fx,
                                                const float* __restrict__ bx,
                                                const float* __restrict__ g,
                                                const float* __restrict__ be,
                                                float* __restrict__ out) {
  const int row = blockIdx.x;
  const int tid = threadIdx.x;
  const int c = tid * 4;
  const float* fr = fx + (size_t)row * C_;
  const float* br = bx + (size_t)row * C_;
  const float4 a = *(const float4*)(fr + c);
  const float4 b = *(const float4*)(br + c);
  float s = a.x + a.y + a.z + a.w + b.x + b.y + b.z + b.w;
  float q = a.x * a.x + a.y * a.y + a.z * a.z + a.w * a.w +
            b.x * b.x + b.y * b.y + b.z * b.z + b.w * b.w;
  s = wave_sum(s);
  q = wave_sum(q);
  __shared__ float r1[4], r2[4];
  if ((tid & 63) == 0) { r1[tid >> 6] = s; r2[tid >> 6] = q; }
  __syncthreads();
  const float sum = r1[0] + r1[1] + r1[2] + r1[3];
  const float sq  = r2[0] + r2[1] + r2[2] + r2[3];
  const float mu  = sum * (1.f / (2 * C_));
  const float var = sq * (1.f / (2 * C_)) - mu * mu;
  const float rs  = rsqrtf(var + 1e-5f);
  float* orow = out + (size_t)row * (2 * C_);
  {
    const float4 gv = *(const float4*)(g + c);
    const float4 bv = *(const float4*)(be + c);
    float4 ov;
    ov.x = (a.x - mu) * rs * gv.x + bv.x;
    ov.y = (a.y - mu) * rs * gv.y + bv.y;
    ov.z = (a.z - mu) * rs * gv.z + bv.z;
    ov.w = (a.w - mu) * rs * gv.w + bv.w;
    *(float4*)(orow + c) = ov;
  }
  {
    const float4 gv = *(const float4*)(g + C_ + c);
    const float4 bv = *(const float4*)(be + C_ + c);
    float4 ov;
    ov.x = (b.x - mu) * rs * gv.x + bv.x;
    ov.y = (b.y - mu) * rs * gv.y + bv.y;
    ov.z = (b.z - mu) * rs * gv.z + bv.z;
    ov.w = (b.w - mu) * rs * gv.w + bv.w;
    *(float4*)(orow + C_ + c) = ov;
  }
}

// ------------------------------------------------- weight transpose [H,C,HS] -> [C,H*HS]
__global__ __launch_bounds__(256) void transpose_whcs(const float* __restrict__ w,
                                                      float* __restrict__ wt) {
  const int idx = blockIdx.x * 256 + threadIdx.x;  // over C_*C_
  const int s = idx & 63;
  const int h = (idx >> 6) & (H_ - 1);
  const int c = idx >> 10;
  wt[idx] = w[((size_t)h * C_ + c) * HS_ + s];
}

// ---------------------------------------------------------------- GEMM (fp32)
// C[M,N] = A[M,K] @ B[K,N] (+bias[N]) (relu?) (+resid[M,N])
// BM=BN=128, BK=8, 256 threads, 8x8 microtile. All of M,N % 128 == 0, K % 8 == 0.
template <bool RELU>
__global__ __launch_bounds__(256) void gemm128(const float* __restrict__ A,
                                               const float* __restrict__ Bm,
                                               float* __restrict__ Cm,
                                               const float* __restrict__ bias,
                                               const float* __restrict__ resid,
                                               int M, int N, int K) {
  __shared__ float As[8][128];
  __shared__ float Bs[8][128];
  const int tid = threadIdx.x;
  const int tx = tid & 15, ty = tid >> 4;
  const int arow = tid >> 1, ac4 = (tid & 1) * 4;
  const int bkk = tid >> 5, bn4 = (tid & 31) * 4;
  const int rowbase = blockIdx.y * 128;
  const int colbase = blockIdx.x * 128;
  const float* Ap = A + (size_t)(rowbase + arow) * K + ac4;
  const float* Bp = Bm + (size_t)bkk * N + colbase + bn4;

  float acc[8][8];
#pragma unroll
  for (int i = 0; i < 8; i++)
#pragma unroll
    for (int j = 0; j < 8; j++) acc[i][j] = 0.f;

  for (int k0 = 0; k0 < K; k0 += 8) {
    const float4 av = *(const float4*)(Ap + k0);
    const float4 bv = *(const float4*)(Bp + (size_t)k0 * N);
    As[ac4 + 0][arow] = av.x;
    As[ac4 + 1][arow] = av.y;
    As[ac4 + 2][arow] = av.z;
    As[ac4 + 3][arow] = av.w;
    *(float4*)&Bs[bkk][bn4] = bv;
    __syncthreads();
#pragma unroll
    for (int kk = 0; kk < 8; kk++) {
      const float4 a0 = *(const float4*)&As[kk][ty * 8];
      const float4 a1 = *(const float4*)&As[kk][ty * 8 + 4];
      const float4 b0 = *(const float4*)&Bs[kk][tx * 4];
      const float4 b1 = *(const float4*)&Bs[kk][64 + tx * 4];
      const float am[8] = {a0.x, a0.y, a0.z, a0.w, a1.x, a1.y, a1.z, a1.w};
      const float bm[8] = {b0.x, b0.y, b0.z, b0.w, b1.x, b1.y, b1.z, b1.w};
#pragma unroll
      for (int i = 0; i < 8; i++)
#pragma unroll
        for (int j = 0; j < 8; j++) acc[i][j] = fmaf(am[i], bm[j], acc[i][j]);
    }
    __syncthreads();
  }

#pragma unroll
  for (int i = 0; i < 8; i++) {
    const int row = rowbase + ty * 8 + i;
#pragma unroll
    for (int half = 0; half < 2; half++) {
      const int col = colbase + half * 64 + tx * 4;
      float4 r;
      r.x = acc[i][half * 4 + 0];
      r.y = acc[i][half * 4 + 1];
      r.z = acc[i][half * 4 + 2];
      r.w = acc[i][half * 4 + 3];
      if (bias) {
        const float4 bb = *(const float4*)(bias + col);
        r.x += bb.x; r.y += bb.y; r.z += bb.z; r.w += bb.w;
      }
      if (RELU) {
        r.x = fmaxf(r.x, 0.f); r.y = fmaxf(r.y, 0.f);
        r.z = fmaxf(r.z, 0.f); r.w = fmaxf(r.w, 0.f);
      }
      if (resid) {
        const float4 rr = *(const float4*)(resid + (size_t)row * N + col);
        r.x += rr.x; r.y += rr.y; r.z += rr.z; r.w += rr.w;
      }
      *(float4*)(Cm + (size_t)row * N + col) = r;
    }
  }
}

// ---------------------------------------------------------------- attention
// q,k,v,o: flat [B*T, C] with column = h*HS + s.  One block per (b,h,4 queries).
__global__ __launch_bounds__(256) void attn4(const float* __restrict__ q,
                                             const float* __restrict__ k,
                                             const float* __restrict__ v,
                                             float* __restrict__ o) {
  const int t0 = blockIdx.x * 4;
  const int h = blockIdx.y;
  const int b = blockIdx.z;
  const int tid = threadIdx.x;
  const size_t base = (size_t)b * T_ * C_ + (size_t)h * HS_;

  __shared__ float qs[4][HS_];
  __shared__ float sc[4][T_];
  __shared__ float part[4][4][HS_];

  {
    const int qi = tid >> 6, s = tid & 63;
    qs[qi][s] = q[base + (size_t)(t0 + qi) * C_ + s];
  }
  __syncthreads();

  // pass 1: scores  sc[qi][u] = (q_qi . k_u) / sqrt(C)
  for (int u = tid; u < T_; u += 256) {
    const float* kr = k + base + (size_t)u * C_;
    float a0 = 0.f, a1 = 0.f, a2 = 0.f, a3 = 0.f;
#pragma unroll
    for (int s4 = 0; s4 < HS_; s4 += 4) {
      const float4 kv = *(const float4*)(kr + s4);
      a0 += qs[0][s4] * kv.x + qs[0][s4 + 1] * kv.y + qs[0][s4 + 2] * kv.z + qs[0][s4 + 3] * kv.w;
      a1 += qs[1][s4] * kv.x + qs[1][s4 + 1] * kv.y + qs[1][s4 + 2] * kv.z + qs[1][s4 + 3] * kv.w;
      a2 += qs[2][s4] * kv.x + qs[2][s4 + 1] * kv.y + qs[2][s4 + 2] * kv.z + qs[2][s4 + 3] * kv.w;
      a3 += qs[3][s4] * kv.x + qs[3][s4 + 1] * kv.y + qs[3][s4 + 2] * kv.z + qs[3][s4 + 3] * kv.w;
    }
    sc[0][u] = a0 * 0.03125f;
    sc[1][u] = a1 * 0.03125f;
    sc[2][u] = a2 * 0.03125f;
    sc[3][u] = a3 * 0.03125f;
  }
  __syncthreads();

  // softmax: wave w owns row w (wave-local reduce, no block sync needed)
  {
    const int w = tid >> 6, lane = tid & 63;
    float m = -1e30f;
    for (int u = lane; u < T_; u += 64) m = fmaxf(m, sc[w][u]);
    m = wave_max(m);
    float ssum = 0.f;
    for (int u = lane; u < T_; u += 64) {
      const float e = __expf(sc[w][u] - m);
      sc[w][u] = e;
      ssum += e;
    }
    ssum = wave_sum(ssum);
    const float inv = 1.f / ssum;
    for (int u = lane; u < T_; u += 64) sc[w][u] *= inv;
  }
  __syncthreads();

  // pass 2: o[qi][s] = sum_u sc[qi][u] * v[u][s]; 4 key-groups reduced via LDS
  {
    const int g = tid >> 6, s = tid & 63;
    float a0 = 0.f, a1 = 0.f, a2 = 0.f, a3 = 0.f;
    const int u0 = g * 256;
    for (int u = u0; u < u0 + 256; u++) {
      const float vv = v[base + (size_t)u * C_ + s];
      a0 += sc[0][u] * vv;
      a1 += sc[1][u] * vv;
      a2 += sc[2][u] * vv;
      a3 += sc[3][u] * vv;
    }
    part[g][0][s] = a0;
    part[g][1][s] = a1;
    part[g][2][s] = a2;
    part[g][3][s] = a3;
  }
  __syncthreads();
  {
    const int qi = tid >> 6, s = tid & 63;
    const float r = part[0][qi][s] + part[1][qi][s] + part[2][qi][s] + part[3][qi][s];
    o[base + (size_t)(t0 + qi) * C_ + s] = r;
  }
}

// ---------------------------------------------------------------- launch
extern "C" void kernel_launch(void* const* d_in, const int* in_sizes, int n_in,
                              void* d_out, int out_size, void* d_ws, size_t ws_size,
                              hipStream_t stream) {
  const float* x      = (const float*)d_in[0];
  const float* f_Wq   = (const float*)d_in[1];
  const float* f_bq   = (const float*)d_in[2];
  const float* f_Wk   = (const float*)d_in[3];
  const float* f_bk   = (const float*)d_in[4];
  const float* f_Wv   = (const float*)d_in[5];
  const float* f_bv   = (const float*)d_in[6];
  const float* f_Wp   = (const float*)d_in[7];
  const float* f_bp   = (const float*)d_in[8];
  const float* b_Wq   = (const float*)d_in[9];
  const float* b_bq   = (const float*)d_in[10];
  const float* b_Wk   = (const float*)d_in[11];
  const float* b_bk   = (const float*)d_in[12];
  const float* b_Wv   = (const float*)d_in[13];
  const float* b_bv   = (const float*)d_in[14];
  const float* b_Wp   = (const float*)d_in[15];
  const float* b_bp   = (const float*)d_in[16];
  const float* f_ln_g = (const float*)d_in[17];
  const float* f_ln_b = (const float*)d_in[18];
  const float* b_ln_g = (const float*)d_in[19];
  const float* b_ln_b = (const float*)d_in[20];
  const float* ln2_g  = (const float*)d_in[21];
  const float* ln2_b  = (const float*)d_in[22];
  const float* W1     = (const float*)d_in[23];
  const float* b1     = (const float*)d_in[24];
  const float* W2     = (const float*)d_in[25];
  const float* b2     = (const float*)d_in[26];
  float* out = (float*)d_out;
  float* ws = (float*)d_ws;

  // workspace layout (floats); total = 7*BTC = 224 MiB
  float* LNB = ws;                    // [B*T, C]   LN output (per direction)
  float* Qb  = ws + 1 * BTC;          // [B*T, C]
  float* Kb  = ws + 2 * BTC;          // [B*T, C]
  float* Vb  = ws + 3 * BTC;          // [B*T, C]
  float* Ob  = ws + 4 * BTC;          // [B*T, C]  (first C_*C_ also reused as WT)
  float* FX  = ws + 5 * BTC;          // [B*T, C]   forward branch out
  float* BX  = ws + 6 * BTC;          // [B*T, C]   backward branch out
  float* WT  = ws + 4 * BTC;          // [C, C] transposed QKV weight (inside Ob slot,
                                      //   only live before attn writes Ob)
  float* HLN = ws;                    // [B*T, 2C]  (reuses LNB+Qb after both branches)
  float* MID = ws + 2 * BTC;          // [1024, 8C] FFN mid chunk (reuses Kb)

  const dim3 blk(256);
  const int rows = B_ * T_;           // 8192
  const dim3 gq(C_ / 128, rows / 128);
  const dim3 gt(C_ * C_ / 256);
  const dim3 ga(T_ / 4, H_, B_);

  // ---- forward branch
  ln_rows<false><<<rows, blk, 0, stream>>>(x, f_ln_g, f_ln_b, LNB);
  transpose_whcs<<<gt, blk, 0, stream>>>(f_Wq, WT);
  gemm128<false><<<gq, blk, 0, stream>>>(LNB, WT, Qb, f_bq, nullptr, rows, C_, C_);
  transpose_whcs<<<gt, blk, 0, stream>>>(f_Wk, WT);
  gemm128<false><<<gq, blk, 0, stream>>>(LNB, WT, Kb, f_bk, nullptr, rows, C_, C_);
  transpose_whcs<<<gt, blk, 0, stream>>>(f_Wv, WT);
  gemm128<false><<<gq, blk, 0, stream>>>(LNB, WT, Vb, f_bv, nullptr, rows, C_, C_);
  attn4<<<ga, blk, 0, stream>>>(Qb, Kb, Vb, Ob);
  gemm128<false><<<gq, blk, 0, stream>>>(Ob, f_Wp, FX, f_bp, LNB, rows, C_, C_);

  // ---- backward branch (channel-flipped input)
  ln_rows<true><<<rows, blk, 0, stream>>>(x, b_ln_g, b_ln_b, LNB);
  transpose_whcs<<<gt, blk, 0, stream>>>(b_Wq, WT);
  gemm128<false><<<gq, blk, 0, stream>>>(LNB, WT, Qb, b_bq, nullptr, rows, C_, C_);
  transpose_whcs<<<gt, blk, 0, stream>>>(b_Wk, WT);
  gemm128<false><<<gq, blk, 0, stream>>>(LNB, WT, Kb, b_bk, nullptr, rows, C_, C_);
  transpose_whcs<<<gt, blk, 0, stream>>>(b_Wv, WT);
  gemm128<false><<<gq, blk, 0, stream>>>(LNB, WT, Vb, b_bv, nullptr, rows, C_, C_);
  attn4<<<ga, blk, 0, stream>>>(Qb, Kb, Vb, Ob);
  gemm128<false><<<gq, blk, 0, stream>>>(Ob, b_Wp, BX, b_bp, LNB, rows, C_, C_);

  // ---- concat + LN2
  ln2_rows<<<rows, blk, 0, stream>>>(FX, BX, ln2_g, ln2_b, HLN);

  // ---- FFN in 8 row-chunks of 1024 (keeps mid buffer at 32 MB)
  for (int ch = 0; ch < 8; ch++) {
    const float* hch = HLN + (size_t)ch * 1024 * (2 * C_);
    float* och = out + (size_t)ch * 1024 * (2 * C_);
    gemm128<true><<<dim3(8 * C_ / 128, 1024 / 128), blk, 0, stream>>>(
        hch, W1, MID, b1, nullptr, 1024, 8 * C_, 2 * C_);
    gemm128<false><<<dim3(2 * C_ / 128, 1024 / 128), blk, 0, stream>>>(
        MID, W2, och, b2, hch, 1024, 2 * C_, 8 * C_);
  }
}